// Round 4
// 153.418 us; speedup vs baseline: 1.0358x; 1.0358x over previous
//
#include <hip/hip_runtime.h>
#include <math.h>

#define TEMP_INV (1.0f / 0.07f)
#define WEIGHT 0.5f
#define EPS 1e-8f
#define BB 64
#define TT 512
#define DD 512
#define RR 4                 // rows per chunk
#define NC 4                 // chunks per wave -> 16 rows/wave
#define ROWS_PER_WAVE (RR * NC)
#define XBLK (TT / (4 * ROWS_PER_WAVE))   // 8 blocks along T
#define NBLK (XBLK * BB * 2)              // 1024 total blocks
// DO NOT retune RR/NC: RR4xNC4 is the ONLY config where the compiler keeps
// the ping-pong buffers live (VGPR 44, 52.6 us streaming). RR2xNC4 and
// RR4xNC2 both collapse to VGPR 32 / serialized loads and regress 12-20%
// (R11, R12 of prior session).

typedef float f32x4 __attribute__((ext_vector_type(4)));

__device__ inline float wave_sum(float v) {
    for (int o = 32; o >= 1; o >>= 1) v += __shfl_xor(v, o, 64);
    return v;
}
__device__ inline int wave_max_i(int v) {
    for (int o = 32; o >= 1; o >>= 1) v = max(v, __shfl_xor(v, o, 64));
    return v;
}
__device__ inline int wave_min_i(int v) {
    for (int o = 32; o >= 1; o >>= 1) v = min(v, __shfl_xor(v, o, 64));
    return v;
}

#define LOADC(B0, B1, CH)                                                   \
    _Pragma("unroll")                                                       \
    for (int r = 0; r < RR; r++) {                                          \
        const float* row_ = base + (size_t)(t0 + (CH) * RR + r) * DD;       \
        B0[r] = *(const f32x4*)(row_ + lane * 4);                           \
        B1[r] = *(const f32x4*)(row_ + 256 + lane * 4);                     \
    }

#define COMPC(B0, B1, CH)                                                   \
    _Pragma("unroll")                                                       \
    for (int r = 0; r < RR; r++) {                                          \
        const int k_ = (CH) * RR + r;                                       \
        dot[k_] = B0[r].x * c0.x + B0[r].y * c0.y + B0[r].z * c0.z          \
                + B0[r].w * c0.w + B1[r].x * c1.x + B1[r].y * c1.y          \
                + B1[r].z * c1.z + B1[r].w * c1.w;                          \
        nrm[k_] = B0[r].x * B0[r].x + B0[r].y * B0[r].y + B0[r].z * B0[r].z \
                + B0[r].w * B0[r].w + B1[r].x * B1[r].x + B1[r].y * B1[r].y \
                + B1[r].z * B1[r].z + B1[r].w * B1[r].w;                    \
    }

// R13 (3rd resubmit after broker timeouts): FUSED single-dispatch pipeline.
// The 3-kernel version spent ~106 us of its 158.9 us total outside
// sims_kernel (prep + finalize + 2 launch gaps). Each block now recomputes
// idx from the mask (2 KB, 16x redundant, L2/L3-hit) and builds its
// normalized anchor via LDS; negative partials leave via agent-scope
// atomic stores (L2-bypassing => cross-XCD coherent WITHOUT a
// wbl2-emitting release fence, which was the prior session's
// "fence-ticket" regression); an s_waitcnt vmcnt(0) + relaxed ticket lets
// the last block finalize in-kernel. Streaming core (ping-pong LOADC/COMPC
// + batched butterfly) is byte-identical to the proven 52.6 us structure.
__global__ __launch_bounds__(256) void fused_kernel(
    const float* __restrict__ video, const float* __restrict__ audio,
    const int* __restrict__ mask,
    float* __restrict__ pos, float* __restrict__ part,
    unsigned int* __restrict__ counter, float* __restrict__ out)
{
    const int b = blockIdx.y;
    const int dir = blockIdx.z;
    const int tid = threadIdx.x;
    const int wid = tid >> 6, lane = tid & 63;
    const int t0 = blockIdx.x * (4 * ROWS_PER_WAVE) + wid * ROWS_PER_WAVE;

    __shared__ int sh_i[4];
    __shared__ float sh_f[4][3];
    __shared__ int s_idx;
    __shared__ float s_anc[DD];
    __shared__ float s_inv;
    __shared__ int s_last;

    // ---- phase 1: idx = argmax(mask[b]) (first max), per-block ----
    int m0 = mask[b * TT + tid];
    int m1 = mask[b * TT + tid + 256];
    int vmax = wave_max_i(max(m0, m1));
    if (lane == 0) sh_i[wid] = vmax;
    __syncthreads();
    if (tid == 0) {
        int r = sh_i[0];
        for (int i = 1; i < 4; i++) r = max(r, sh_i[i]);
        sh_i[0] = r;
    }
    __syncthreads();
    vmax = sh_i[0];
    __syncthreads();
    int cand = (m0 == vmax) ? tid : 0x7fffffff;
    int cand1 = (m1 == vmax) ? (tid + 256) : 0x7fffffff;
    cand = min(cand, cand1);
    cand = wave_min_i(cand);
    if (lane == 0) sh_i[wid] = cand;
    __syncthreads();
    if (tid == 0) {
        int r = sh_i[0];
        for (int i = 1; i < 4; i++) r = min(r, sh_i[i]);
        s_idx = r;
    }
    __syncthreads();
    const int idx = s_idx;

    // ---- phase 1b: other-modality anchor, normalized in LDS ----
    const float* base = (dir == 0 ? video : audio) + (size_t)b * TT * DD;
    const float* ancrow = (dir == 0 ? audio : video) + (size_t)(b * TT + idx) * DD;

    float a0 = ancrow[tid], a1 = ancrow[tid + 256];
    s_anc[tid] = a0;
    s_anc[tid + 256] = a1;
    float ss = a0 * a0 + a1 * a1;
    float sso = 0.0f, dav = 0.0f;
    const bool posduty = (blockIdx.x == 0) && (dir == 0);  // one block per b
    if (posduty) {
        const float* vrow = video + (size_t)(b * TT + idx) * DD;
        float o0 = vrow[tid], o1 = vrow[tid + 256];
        sso = o0 * o0 + o1 * o1;
        dav = a0 * o0 + a1 * o1;
    }
    ss = wave_sum(ss);
    sso = wave_sum(sso);
    dav = wave_sum(dav);
    if (lane == 0) { sh_f[wid][0] = ss; sh_f[wid][1] = sso; sh_f[wid][2] = dav; }
    __syncthreads();
    if (tid == 0) {
        float ra = 0.f, ro = 0.f, rd = 0.f;
        for (int i = 0; i < 4; i++) { ra += sh_f[i][0]; ro += sh_f[i][1]; rd += sh_f[i][2]; }
        float inva = 1.0f / fmaxf(sqrtf(ra), EPS);
        s_inv = inva;
        if (posduty) {
            float invo = 1.0f / fmaxf(sqrtf(ro), EPS);
            __hip_atomic_store(&pos[b], rd * inva * invo * TEMP_INV,
                               __ATOMIC_RELAXED, __HIP_MEMORY_SCOPE_AGENT);
        }
    }
    __syncthreads();
    const float inv = s_inv;
    f32x4 c0 = ((const f32x4*)s_anc)[lane] * inv;
    f32x4 c1 = ((const f32x4*)(s_anc + 256))[lane] * inv;

    // ---- phase 2: proven streaming core (unchanged) ----
    f32x4 pa0[RR], pa1[RR], pb0[RR], pb1[RR];
    float dot[ROWS_PER_WAVE], nrm[ROWS_PER_WAVE];

    LOADC(pa0, pa1, 0)          // chunk 0 in flight
    LOADC(pb0, pb1, 1)          // chunk 1 in flight
    COMPC(pa0, pa1, 0)          // consume 0
    LOADC(pa0, pa1, 2)          // chunk 2 in flight
    COMPC(pb0, pb1, 1)          // consume 1
    LOADC(pb0, pb1, 3)          // chunk 3 in flight
    COMPC(pa0, pa1, 2)          // consume 2
    COMPC(pb0, pb1, 3)          // consume 3

    // one batched butterfly: 6 levels x 32 independent shfl-adds
#pragma unroll
    for (int o = 32; o >= 1; o >>= 1) {
#pragma unroll
        for (int k = 0; k < ROWS_PER_WAVE; k++) {
            dot[k] += __shfl_xor(dot[k], o, 64);
            nrm[k] += __shfl_xor(nrm[k], o, 64);
        }
    }

    // ---- phase 3: per-block partial, ticket, last-block finalize ----
    if (lane == 0) {
        const int idx2 = idx;
        float local = 0.0f;
#pragma unroll
        for (int k = 0; k < ROWS_PER_WAVE; k++) {
            const int t = t0 + k;
            float sim = dot[k] / fmaxf(sqrtf(nrm[k]), EPS) * TEMP_INV;
            local += (t == idx2) ? 0.0f : expf(sim);
        }
        sh_f[wid][0] = local;
    }
    __syncthreads();
    if (tid == 0) {
        float p = sh_f[0][0] + sh_f[1][0] + sh_f[2][0] + sh_f[3][0];
        const int bid_flat = (dir * BB + b) * XBLK + blockIdx.x;
        __hip_atomic_store(&part[bid_flat], p,
                           __ATOMIC_RELAXED, __HIP_MEMORY_SCOPE_AGENT);
        // all this wave's coherent stores (incl. pos, if posduty) complete
        // at the device coherence point before the ticket increments:
        asm volatile("s_waitcnt vmcnt(0)" ::: "memory");
        unsigned old = __hip_atomic_fetch_add(counter, 1u,
                                              __ATOMIC_RELAXED, __HIP_MEMORY_SCOPE_AGENT);
        s_last = (old == (unsigned)(NBLK - 1)) ? 1 : 0;
    }
    __syncthreads();
    if (s_last && wid == 0) {
        // 64 lanes, one batch element each
        float na = 0.f, nv = 0.f;
#pragma unroll
        for (int x = 0; x < XBLK; x++)
            na += __hip_atomic_load(&part[(0 * BB + lane) * XBLK + x],
                                    __ATOMIC_RELAXED, __HIP_MEMORY_SCOPE_AGENT);
#pragma unroll
        for (int x = 0; x < XBLK; x++)
            nv += __hip_atomic_load(&part[(1 * BB + lane) * XBLK + x],
                                    __ATOMIC_RELAXED, __HIP_MEMORY_SCOPE_AGENT);
        float p = __hip_atomic_load(&pos[lane],
                                    __ATOMIC_RELAXED, __HIP_MEMORY_SCOPE_AGENT);
        float term = WEIGHT * (logf(na) + logf(nv)) - p;
        term = wave_sum(term);
        if (lane == 0) out[0] = term * (1.0f / (float)BB);
    }
}

extern "C" void kernel_launch(void* const* d_in, const int* in_sizes, int n_in,
                              void* d_out, int out_size, void* d_ws, size_t ws_size,
                              hipStream_t stream)
{
    const float* video = (const float*)d_in[0];
    const float* audio = (const float*)d_in[1];
    const int* mask = (const int*)d_in[2];

    float* ws = (float*)d_ws;
    float* pos = ws;                          // 64 floats
    float* part = ws + BB;                    // 1024 floats
    unsigned int* counter = (unsigned int*)(part + NBLK);

    // reset ticket (4 bytes, graph-capturable node)
    hipMemsetAsync(counter, 0, sizeof(unsigned int), stream);

    dim3 grid(XBLK, BB, 2);
    fused_kernel<<<grid, 256, 0, stream>>>(video, audio, mask, pos, part, counter, (float*)d_out);
}